// Round 17
// baseline (129.835 us; speedup 1.0000x reference)
//
#include <hip/hip_runtime.h>
#include <math.h>

#define T_ 4096
#define C_ 768
#define H_ 12
#define D_ 64
#define TC_ ((size_t)T_ * C_)
#define CC_ ((size_t)C_ * C_)

typedef __attribute__((ext_vector_type(8))) __bf16 bf16x8;
typedef __attribute__((ext_vector_type(4))) __bf16 bf16x4;
typedef __attribute__((ext_vector_type(2))) __bf16 bf16x2;
typedef __attribute__((ext_vector_type(4))) float f32x4;
typedef __attribute__((ext_vector_type(16))) float f32x16;
typedef __attribute__((ext_vector_type(8))) unsigned short u16x8;
typedef __attribute__((ext_vector_type(4))) unsigned int u32x4;

// Softmax shift folded out entirely: p = exp2(s) (scores in log2 units,
// |s| <~ 8.5 -> p <= ~362, l <= ~7e3; uniform factor cancels in O/l).

static __device__ __forceinline__ float fast_exp2(float x) {
#if __has_builtin(__builtin_amdgcn_exp2f)
    return __builtin_amdgcn_exp2f(x);
#else
    return exp2f(x);
#endif
}

static __device__ __forceinline__ float fast_rcp(float x) {
#if __has_builtin(__builtin_amdgcn_rcpf)
    return __builtin_amdgcn_rcpf(x);   // ~1ulp approx; fine for normalization
#else
    return 1.0f / x;
#endif
}

// pack two f32 -> u32 of 2 bf16 (compiler emits v_cvt_pk_bf16_f32)
static __device__ __forceinline__ unsigned pack2(float a, float b) {
    bf16x2 v = { (__bf16)a, (__bf16)b };
    return __builtin_bit_cast(unsigned, v);
}

// global (16B per lane) -> LDS direct, wave-uniform LDS base + lane*16
static __device__ __forceinline__ void gload16(const void* g, void* l) {
    __builtin_amdgcn_global_load_lds(
        (const __attribute__((address_space(1))) unsigned int*)g,
        (__attribute__((address_space(3))) unsigned int*)l, 16, 0, 0);
}

// ---------------------------------------------------------------------------
// fp32 -> bf16 convert (RNE), n4 = n/4
// ---------------------------------------------------------------------------
__global__ void f2b_kernel(const float* __restrict__ in,
                           unsigned short* __restrict__ out, int n4) {
    int i = blockIdx.x * blockDim.x + threadIdx.x;
    const int stride = gridDim.x * blockDim.x;
    for (; i < n4; i += stride) {
        float4 v = ((const float4*)in)[i];
        bf16x4 o = { (__bf16)v.x, (__bf16)v.y, (__bf16)v.z, (__bf16)v.w };
        *(bf16x4*)&out[(size_t)i * 4] = o;
    }
}

// 4 weight matrices (each CC_ elems) in one launch; dst contiguous at out+y*CC_
__global__ void f2b4_kernel(const float* __restrict__ w0, const float* __restrict__ w1,
                            const float* __restrict__ w2, const float* __restrict__ w3,
                            unsigned short* __restrict__ out) {
    const float* src = (blockIdx.y == 0) ? w0 : (blockIdx.y == 1) ? w1
                     : (blockIdx.y == 2) ? w2 : w3;
    unsigned short* dst = out + (size_t)blockIdx.y * CC_;
    const int i = blockIdx.x * blockDim.x + threadIdx.x;   // < CC_/4
    float4 v = ((const float4*)src)[i];
    bf16x4 o = { (__bf16)v.x, (__bf16)v.y, (__bf16)v.z, (__bf16)v.w };
    *(bf16x4*)&dst[(size_t)i * 4] = o;
}

// ---------------------------------------------------------------------------
// m97-style 128x128 GEMM core + XOR-swizzled LDS (verified r15/r16).
// LDS block b of row r holds global 8-elem block b^(r&7); read col
// (ks*32+lg*8)^((lq&7)<<3); gload16 dest linear (rule #21).
// ---------------------------------------------------------------------------
#define BM 128
#define BN 128
#define BKG 64

struct GemmRegs {
    const unsigned short* ag[4];
    const unsigned short* wg[4];
    unsigned short* la[4];
    unsigned short* lw[4];
    int lq, lg, wr, wc;
};

static __device__ __forceinline__ void gemm_setup(
    GemmRegs& R, const unsigned short* A, const unsigned short* W,
    unsigned short* Asm, unsigned short* Bsm, int bm, int bn, int K)
{
    const int tid = threadIdx.x;
    const int wave = tid >> 6, lane = tid & 63;
    R.lq = lane & 15; R.lg = lane >> 4;
    R.wr = wave >> 1; R.wc = wave & 1;
#pragma unroll
    for (int i = 0; i < 4; ++i) {
        const int flat = wave * 256 + i * 64 + lane;   // 0..1023
        const int row = flat >> 3;
        const int col = ((flat & 7) * 8) ^ ((row & 7) << 3);   // pre-swizzled src
        R.ag[i] = A + (size_t)(bm + row) * K + col;
        R.wg[i] = W + (size_t)(bn + row) * K + col;
        R.la[i] = Asm + (wave * 4 + i) * 512;
        R.lw[i] = Bsm + (wave * 4 + i) * 512;
    }
}

static __device__ __forceinline__ void gemm_mfma_step(
    GemmRegs& R, unsigned short* Asm, unsigned short* Bsm,
    const int colA[2], f32x4 acc[4][4])
{
    __builtin_amdgcn_s_setprio(1);
#pragma unroll
    for (int ks = 0; ks < 2; ++ks) {
        bf16x8 af[4], wf[4];
#pragma unroll
        for (int m = 0; m < 4; ++m)
            af[m] = *(const bf16x8*)&Asm[(R.wr * 64 + m * 16 + R.lq) * BKG + colA[ks]];
#pragma unroll
        for (int n = 0; n < 4; ++n)
            wf[n] = *(const bf16x8*)&Bsm[(R.wc * 64 + n * 16 + R.lq) * BKG + colA[ks]];
#pragma unroll
        for (int m = 0; m < 4; ++m)
#pragma unroll
            for (int n = 0; n < 4; ++n)
                acc[m][n] = __builtin_amdgcn_mfma_f32_16x16x32_bf16(af[m], wf[n], acc[m][n], 0, 0, 0);
    }
    __builtin_amdgcn_s_setprio(0);
}

static __device__ __forceinline__ void gemm_loop(
    GemmRegs& R, unsigned short* Asm, unsigned short* Bsm, int K, f32x4 acc[4][4])
{
    const int sw = (R.lq & 7) << 3;
    int colA[2];
#pragma unroll
    for (int ks = 0; ks < 2; ++ks)
        colA[ks] = (ks * 32 + R.lg * 8) ^ sw;
    for (int kb = 0; kb < K; kb += BKG) {
        __syncthreads();   // previous tile fully consumed
#pragma unroll
        for (int i = 0; i < 4; ++i) {
            gload16(R.ag[i] + kb, R.la[i]);
            gload16(R.wg[i] + kb, R.lw[i]);
        }
        __syncthreads();   // staged
        gemm_mfma_step(R, Asm, Bsm, colA, acc);
    }
}

// Fused QKV projection: z selects {Q (scaled), K, V (head-transposed)}.
// V stores with kv bits 2<->3 swapped per 16-t group (PV slot permutation,
// verified r16) so attn's PV B-frag is the lane's OWN registers.
__global__ __launch_bounds__(256) void qkv128(
    const unsigned short* __restrict__ xb,
    const unsigned short* __restrict__ Wqb, const unsigned short* __restrict__ Wkb,
    const unsigned short* __restrict__ Wvb,
    const float* __restrict__ bq, const float* __restrict__ bk, const float* __restrict__ bv,
    unsigned short* __restrict__ Qb, unsigned short* __restrict__ Kb,
    unsigned short* __restrict__ Vtb)
{
    __shared__ unsigned short Asm[BM * BKG];
    __shared__ unsigned short Bsm[BN * BKG];
    const int z = blockIdx.z;
    const unsigned short* W = (z == 0) ? Wqb : (z == 1) ? Wkb : Wvb;
    const float* bias = (z == 0) ? bq : (z == 1) ? bk : bv;
    const int bm = blockIdx.x * BM, bn = blockIdx.y * BN;

    GemmRegs R;
    gemm_setup(R, xb, W, Asm, Bsm, bm, bn, C_);
    f32x4 acc[4][4] = {};
    gemm_loop(R, Asm, Bsm, C_, acc);

    // 0.125 * log2(e): QK^T scores land in log2 domain
    const float sc = (z == 0) ? 0.18033688011112042f : 1.0f;
#pragma unroll
    for (int mt = 0; mt < 4; ++mt) {
        const int m0 = bm + R.wr * 64 + mt * 16 + R.lg * 4;
#pragma unroll
        for (int nt = 0; nt < 4; ++nt) {
            const int n = bn + R.wc * 64 + nt * 16 + R.lq;
            const float b = bias[n];
            if (z == 2) {
                const int tp = (m0 & ~12) | ((m0 & 4) << 1) | ((m0 & 8) >> 1);
                bf16x4 o = { (__bf16)(acc[mt][nt][0] + b), (__bf16)(acc[mt][nt][1] + b),
                             (__bf16)(acc[mt][nt][2] + b), (__bf16)(acc[mt][nt][3] + b) };
                *(bf16x4*)&Vtb[(size_t)n * T_ + tp] = o;
            } else {
                unsigned short* Y = (z == 0) ? Qb : Kb;
#pragma unroll
                for (int r = 0; r < 4; ++r)
                    Y[(size_t)(m0 + r) * C_ + n] =
                        __builtin_bit_cast(unsigned short, (__bf16)((acc[mt][nt][r] + b) * sc));
            }
        }
    }
}

// ---------------------------------------------------------------------------
// Output projection with FUSED split-combine: A[t][h*64+d] =
// (sum_s Opart[s][h][t][d]) / (sum_s lpart[s][h][t]), computed during
// reg-staging and ds_written into the SAME swizzled LDS slots the verified
// read side expects. K-tiles are 64-aligned -> each K-step is one head.
// ---------------------------------------------------------------------------
template <int S>
__global__ __launch_bounds__(256) void outc128(
    const unsigned short* __restrict__ Opart, const float* __restrict__ lpart,
    const unsigned short* __restrict__ Wob, const float* __restrict__ bo,
    float* __restrict__ out)
{
    __shared__ unsigned short Asm[BM * BKG];
    __shared__ unsigned short Bsm[BN * BKG];
    const int tid = threadIdx.x;
    const int wave = tid >> 6, lane = tid & 63;
    const int lq = lane & 15, lg = lane >> 4;
    const int wr = wave >> 1, wc = wave & 1;
    const int bm = blockIdx.x * BM, bn = blockIdx.y * BN;

    // A-staging geometry (reg-staged): thread slot f -> row, 8-elem block
    int trow[4], d0[4];
    unsigned short* lda[4];
    const unsigned short* wg[4];
    unsigned short* lw[4];
#pragma unroll
    for (int i = 0; i < 4; ++i) {
        const int flat = wave * 256 + i * 64 + lane;
        const int row = flat >> 3;
        trow[i] = bm + row;
        d0[i] = (((flat & 7) ^ (row & 7)) * 8);          // source block (inverse swz)
        lda[i] = Asm + (size_t)flat * 8;                 // linear LDS slot
        const int colw = ((flat & 7) * 8) ^ ((row & 7) << 3);
        wg[i] = Wob + (size_t)(bn + row) * C_ + colw;
        lw[i] = Bsm + (wave * 4 + i) * 512;
    }
    const int sw = (lq & 7) << 3;
    int colA[2];
#pragma unroll
    for (int ks = 0; ks < 2; ++ks)
        colA[ks] = (ks * 32 + lg * 8) ^ sw;

    f32x4 acc[4][4] = {};

    // prefetch O/l regs for kb=0 (h=0)
    u16x8 oreg[4][S];
    float lv[4];
#pragma unroll
    for (int i = 0; i < 4; ++i) {
        float lsum = 0.f;
#pragma unroll
        for (int s = 0; s < S; ++s) {
            oreg[i][s] = *(const u16x8*)(Opart + ((size_t)(s * H_) * T_ + trow[i]) * 64 + d0[i]);
            lsum += lpart[(size_t)(s * H_) * T_ + trow[i]];
        }
        lv[i] = lsum;
    }

    for (int kb = 0; kb < C_; kb += BKG) {
        __syncthreads();   // previous tile fully consumed
#pragma unroll
        for (int i = 0; i < 4; ++i) {
            const float inv = fast_rcp(lv[i]);
            const bf16x8 b0 = __builtin_bit_cast(bf16x8, oreg[i][0]);
            float v[8];
#pragma unroll
            for (int j = 0; j < 8; ++j) v[j] = (float)b0[j];
#pragma unroll
            for (int s = 1; s < S; ++s) {
                const bf16x8 bs = __builtin_bit_cast(bf16x8, oreg[i][s]);
#pragma unroll
                for (int j = 0; j < 8; ++j) v[j] += (float)bs[j];
            }
            u32x4 pk = { pack2(v[0] * inv, v[1] * inv), pack2(v[2] * inv, v[3] * inv),
                         pack2(v[4] * inv, v[5] * inv), pack2(v[6] * inv, v[7] * inv) };
            *(u32x4*)lda[i] = pk;
            gload16(wg[i] + kb, lw[i]);
        }
        __syncthreads();   // staged (W vmcnt + A lgkm drained)

        // prefetch next head's O/l during MFMA
        if (kb + BKG < C_) {
            const int hn = (kb >> 6) + 1;
#pragma unroll
            for (int i = 0; i < 4; ++i) {
                float lsum = 0.f;
#pragma unroll
                for (int s = 0; s < S; ++s) {
                    oreg[i][s] = *(const u16x8*)(Opart +
                        ((size_t)(s * H_ + hn) * T_ + trow[i]) * 64 + d0[i]);
                    lsum += lpart[(size_t)(s * H_ + hn) * T_ + trow[i]];
                }
                lv[i] = lsum;
            }
        }

        GemmRegs R;   // only the read-side fields are used here
        R.lq = lq; R.lg = lg; R.wr = wr; R.wc = wc;
        gemm_mfma_step(R, Asm, Bsm, colA, acc);
    }

#pragma unroll
    for (int mt = 0; mt < 4; ++mt) {
        const int m0 = bm + wr * 64 + mt * 16 + lg * 4;
#pragma unroll
        for (int nt = 0; nt < 4; ++nt) {
            const int n = bn + wc * 64 + nt * 16 + lq;
            const float b = bo[n];
#pragma unroll
            for (int r = 0; r < 4; ++r)
                out[(size_t)(m0 + r) * C_ + n] = acc[mt][nt][r] + b;
        }
    }
}

// ---------------------------------------------------------------------------
// Flash attention (verified r16 core): 4-wave blocks (QBLK=128), dbuf K/V
// LDS 1 barrier/tile, p = exp2(s), own-register PV B-frags (V permutation
// baked into Vtb), T14 reg-staging. Templated kv-SPLITS; grid = S*384.
// S=4 -> 1536 blocks, 5 resident/CU (LDS cap) ~20 waves/CU.
// ---------------------------------------------------------------------------
template <int S>
__global__ __launch_bounds__(256, 3) void attn32s(
    const unsigned short* __restrict__ Qb, const unsigned short* __restrict__ Kb,
    const unsigned short* __restrict__ Vtb, unsigned short* __restrict__ Opart,
    float* __restrict__ lpart)
{
    __shared__ unsigned short Ks[2][64 * 64];
    __shared__ unsigned short Vs[2][64 * 64];

    const int tid = threadIdx.x;
    const int wave = tid >> 6, lane = tid & 63;
    const int lq = lane & 31, hi = lane >> 5;

    // XCD swizzle over S*384 blocks
    const int perx = (S * 384) / 8;
    const int bid = blockIdx.x;
    const int sw = (bid & 7) * perx + (bid >> 3);
    const int split = sw / 384;
    const int rem = sw - split * 384;
    const int h = rem >> 5, qt = rem & 31;     // 32 q-tiles of 128 per head
    const int q0 = qt * 128 + wave * 32;
    const int kv0 = split * (T_ / S);
    const int KVTILES = T_ / 64 / S;

    const int swz = (lq & 7) << 4;
    int rof[4];
#pragma unroll
    for (int ks = 0; ks < 4; ++ks)
        rof[ks] = lq * 128 + ((hi * 16 + ks * 32) ^ swz);

    // Q B-frags: lane holds Q[q0+lq][ks*16 + hi*8 + i]
    bf16x8 qf[4];
    {
        const unsigned short* qp = Qb + (size_t)(q0 + lq) * C_ + h * D_ + hi * 8;
#pragma unroll
        for (int ks = 0; ks < 4; ++ks) qf[ks] = *(const bf16x8*)(qp + ks * 16);
    }

    // T14 staging, split across 4 waves: slot f = j*256 + tid
    const char* gk[2];
    const char* gv[2];
    char* kds[2];
    char* vds[2];
#pragma unroll
    for (int j = 0; j < 2; ++j) {
        const int f = j * 256 + tid;
        const int row = f >> 3;
        const int col = (f & 7) * 16;
        gk[j] = (const char*)Kb + (size_t)(kv0 + row) * (C_ * 2) + h * (D_ * 2) + col;
        gv[j] = (const char*)Vtb + (size_t)(h * D_ + row) * (T_ * 2) + kv0 * 2 + col;
        kds[j] = (char*)&Ks[0][0] + row * 128 + (col ^ ((row & 7) << 4));
        vds[j] = (char*)&Vs[0][0] + row * 128 + (col ^ ((row & 7) << 4));
    }

    u16x8 kreg[2], vreg[2];
#pragma unroll
    for (int j = 0; j < 2; ++j) {     // tile 0 -> regs
        kreg[j] = *(const u16x8*)(gk[j]);
        vreg[j] = *(const u16x8*)(gv[j]);
    }
#pragma unroll
    for (int j = 0; j < 2; ++j) {     // tile 0 -> buf 0
        *(u16x8*)kds[j] = kreg[j];
        *(u16x8*)vds[j] = vreg[j];
    }
    __syncthreads();
#pragma unroll
    for (int j = 0; j < 2; ++j) {     // tile 1 -> regs
        kreg[j] = *(const u16x8*)(gk[j] + 64 * (C_ * 2));
        vreg[j] = *(const u16x8*)(gv[j] + 128);
    }

    f32x16 oacc0 = {}, oacc1 = {};
    float lrun = 0.f;

    for (int it = 0; it < KVTILES; ++it) {
        const int cur = it & 1;
        const char* kb = (const char*)&Ks[cur][0];
        const char* vb = (const char*)&Vs[cur][0];

        // S^T = K · Q^T
        f32x16 s0 = {}, s1 = {};
        __builtin_amdgcn_s_setprio(1);
#pragma unroll
        for (int ks = 0; ks < 4; ++ks) {
            bf16x8 kf0 = *(const bf16x8*)(kb + rof[ks]);
            bf16x8 kf1 = *(const bf16x8*)(kb + 4096 + rof[ks]);
            s0 = __builtin_amdgcn_mfma_f32_32x32x16_bf16(kf0, qf[ks], s0, 0, 0, 0);
            s1 = __builtin_amdgcn_mfma_f32_32x32x16_bf16(kf1, qf[ks], s1, 0, 0, 0);
        }
        __builtin_amdgcn_s_setprio(0);

        // p = exp2(s)
#pragma unroll
        for (int r = 0; r < 16; ++r) {
            s0[r] = fast_exp2(s0[r]);
            s1[r] = fast_exp2(s1[r]);
        }
        {   // l-sum (off critical path)
            float ps[8];
#pragma unroll
            for (int r = 0; r < 8; ++r)
                ps[r] = (s0[r] + s0[r + 8]) + (s1[r] + s1[r + 8]);
            ps[0] += ps[4]; ps[1] += ps[5]; ps[2] += ps[6]; ps[3] += ps[7];
            float pt = (ps[0] + ps[1]) + (ps[2] + ps[3]);
            lrun += pt + __shfl_xor(pt, 32);
        }

        // P^T B-frags = lane's OWN regs (V slot-permutation in Vtb)
        bf16x8 pf[4];
        {
            u32x4 a0 = { pack2(s0[0], s0[1]), pack2(s0[2], s0[3]),
                         pack2(s0[4], s0[5]), pack2(s0[6], s0[7]) };
            pf[0] = __builtin_bit_cast(bf16x8, a0);
            u32x4 a1 = { pack2(s0[8], s0[9]), pack2(s0[10], s0[11]),
                         pack2(s0[12], s0[13]), pack2(s0[14], s0[15]) };
            pf[1] = __builtin_bit_cast(bf16x8, a1);
            u32x4 a2 = { pack2(s1[0], s1[1]), pack2(s1[2], s1[3]),
                         pack2(s1[4], s1[5]), pack2(s1[6], s1[7]) };
            pf[2] = __builtin_bit_cast(bf16x8, a2);
            u32x4 a3 = { pack2(s1[8], s1[9]), pack2(s1[10], s1[11]),
                         pack2(s1[12], s1[13]), pack2(s1[14], s1[15]) };
            pf[3] = __builtin_bit_cast(bf16x8, a3);
        }

        // PV: O^T += V^T · P^T
        __builtin_amdgcn_s_setprio(1);
#pragma unroll
        for (int ks = 0; ks < 4; ++ks) {
            bf16x8 vf0 = *(const bf16x8*)(vb + rof[ks]);
            bf16x8 vf1 = *(const bf16x8*)(vb + 4096 + rof[ks]);
            oacc0 = __builtin_amdgcn_mfma_f32_32x32x16_bf16(vf0, pf[ks], oacc0, 0, 0, 0);
            oacc1 = __builtin_amdgcn_mfma_f32_32x32x16_bf16(vf1, pf[ks], oacc1, 0, 0, 0);
        }
        __builtin_amdgcn_s_setprio(0);

        // stage tile it+1 regs -> buf[cur^1]; then issue tile it+2 loads.
        if (it + 1 < KVTILES) {
            const int nxt = (cur ^ 1) * 8192;
#pragma unroll
            for (int j = 0; j < 2; ++j) {
                *(u16x8*)(kds[j] + nxt) = kreg[j];
                *(u16x8*)(vds[j] + nxt) = vreg[j];
            }
            if (it + 2 < KVTILES) {
                const size_t ko = (size_t)(it + 2) * 64 * (C_ * 2);
                const size_t vo = (size_t)(it + 2) * 128;
#pragma unroll
                for (int j = 0; j < 2; ++j) {
                    kreg[j] = *(const u16x8*)(gk[j] + ko);
                    vreg[j] = *(const u16x8*)(gv[j] + vo);
                }
            }
        }
        __syncthreads();   // buf[cur^1] staged; all reads of buf[cur] done
    }

    // epilogue: partial (unnormalized) O -> Opart, l -> lpart
    unsigned short* op = Opart + ((size_t)(split * H_ + h) * T_ + q0 + lq) * 64;
#pragma unroll
    for (int k = 0; k < 4; ++k) {
        bf16x4 o0 = { (__bf16)oacc0[4 * k + 0], (__bf16)oacc0[4 * k + 1],
                      (__bf16)oacc0[4 * k + 2], (__bf16)oacc0[4 * k + 3] };
        *(bf16x4*)&op[8 * k + 4 * hi] = o0;
        bf16x4 o1 = { (__bf16)oacc1[4 * k + 0], (__bf16)oacc1[4 * k + 1],
                      (__bf16)oacc1[4 * k + 2], (__bf16)oacc1[4 * k + 3] };
        *(bf16x4*)&op[32 + 8 * k + 4 * hi] = o1;
    }
    if (hi == 0)
        lpart[(size_t)(split * H_ + h) * T_ + q0 + lq] = lrun;
}

// ---------------------------------------------------------------------------
extern "C" void kernel_launch(void* const* d_in, const int* in_sizes, int n_in,
                              void* d_out, int out_size, void* d_ws, size_t ws_size,
                              hipStream_t stream) {
    (void)in_sizes; (void)n_in; (void)out_size;
    const float* x  = (const float*)d_in[0];
    const float* Wq = (const float*)d_in[1];
    const float* bq = (const float*)d_in[2];
    const float* Wk = (const float*)d_in[3];
    const float* bk = (const float*)d_in[4];
    const float* Wv = (const float*)d_in[5];
    const float* bv = (const float*)d_in[6];
    const float* Wo = (const float*)d_in[7];
    const float* bo = (const float*)d_in[8];
    float* out = (float*)d_out;

    unsigned short* ws    = (unsigned short*)d_ws;
    unsigned short* xb    = ws;
    unsigned short* Wqb   = xb + TC_;
    unsigned short* Wkb   = Wqb + CC_;
    unsigned short* Wvb   = Wkb + CC_;
    unsigned short* Wob   = Wvb + CC_;
    unsigned short* Qb    = Wob + CC_;
    unsigned short* Kb    = Qb + TC_;
    unsigned short* Vtb   = Kb + TC_;     // [H][D][T] (t bits 2<->3 swapped per 16)
    unsigned short* Opart = Vtb + TC_;    // [S][H][T][64] bf16

    // choose SPLITS by workspace capacity (ctxb eliminated by fused out-proj)
    const size_t lsz = (size_t)H_ * T_ * sizeof(float);
    const size_t need4 = (size_t)(8 * TC_ + 4 * CC_) * 2 + 4 * lsz;
    const int S = (ws_size >= need4) ? 4 : 2;

    f2b_kernel<<<2048, 256, 0, stream>>>(x, xb, (int)(TC_ / 4));
    dim3 gw(CC_ / 4 / 256, 4);      // all four weights, one launch
    f2b4_kernel<<<gw, 256, 0, stream>>>(Wq, Wk, Wv, Wo, Wqb);

    dim3 gq(T_ / BM, C_ / BN, 3);   // 32 x 6 x 3
    qkv128<<<gq, 256, 0, stream>>>(xb, Wqb, Wkb, Wvb, bq, bk, bv, Qb, Kb, Vtb);

    dim3 go(T_ / BM, C_ / BN);      // 32 x 6
    if (S == 4) {
        float* lpart = (float*)(Opart + 4 * TC_);
        attn32s<4><<<4 * 384, 256, 0, stream>>>(Qb, Kb, Vtb, Opart, lpart);
        outc128<4><<<go, 256, 0, stream>>>(Opart, lpart, Wob, bo, out);
    } else {
        float* lpart = (float*)(Opart + 2 * TC_);
        attn32s<2><<<2 * 384, 256, 0, stream>>>(Qb, Kb, Vtb, Opart, lpart);
        outc128<2><<<go, 256, 0, stream>>>(Opart, lpart, Wob, bo, out);
    }
}

// Round 18
// 125.972 us; speedup vs baseline: 1.0307x; 1.0307x over previous
//
#include <hip/hip_runtime.h>
#include <math.h>

#define T_ 4096
#define C_ 768
#define H_ 12
#define D_ 64
#define TC_ ((size_t)T_ * C_)
#define CC_ ((size_t)C_ * C_)

typedef __attribute__((ext_vector_type(8))) __bf16 bf16x8;
typedef __attribute__((ext_vector_type(4))) __bf16 bf16x4;
typedef __attribute__((ext_vector_type(2))) __bf16 bf16x2;
typedef __attribute__((ext_vector_type(4))) float f32x4;
typedef __attribute__((ext_vector_type(16))) float f32x16;
typedef __attribute__((ext_vector_type(8))) unsigned short u16x8;
typedef __attribute__((ext_vector_type(4))) unsigned int u32x4;

// Softmax shift folded out entirely: p = exp2(s) (scores in log2 units,
// |s| <~ 8.5 -> p <= ~362, l <= ~7e3; uniform factor cancels in O/l).

static __device__ __forceinline__ float fast_exp2(float x) {
#if __has_builtin(__builtin_amdgcn_exp2f)
    return __builtin_amdgcn_exp2f(x);
#else
    return exp2f(x);
#endif
}

// pack two f32 -> u32 of 2 bf16 (compiler emits v_cvt_pk_bf16_f32)
static __device__ __forceinline__ unsigned pack2(float a, float b) {
    bf16x2 v = { (__bf16)a, (__bf16)b };
    return __builtin_bit_cast(unsigned, v);
}

// global (16B per lane) -> LDS direct, wave-uniform LDS base + lane*16
static __device__ __forceinline__ void gload16(const void* g, void* l) {
    __builtin_amdgcn_global_load_lds(
        (const __attribute__((address_space(1))) unsigned int*)g,
        (__attribute__((address_space(3))) unsigned int*)l, 16, 0, 0);
}

// ---------------------------------------------------------------------------
// 4 weight matrices (each CC_ elems) in one launch; dst contiguous at out+y*CC_
// ---------------------------------------------------------------------------
__global__ void f2b4_kernel(const float* __restrict__ w0, const float* __restrict__ w1,
                            const float* __restrict__ w2, const float* __restrict__ w3,
                            unsigned short* __restrict__ out) {
    const float* src = (blockIdx.y == 0) ? w0 : (blockIdx.y == 1) ? w1
                     : (blockIdx.y == 2) ? w2 : w3;
    unsigned short* dst = out + (size_t)blockIdx.y * CC_;
    const int i = blockIdx.x * blockDim.x + threadIdx.x;   // < CC_/4
    float4 v = ((const float4*)src)[i];
    bf16x4 o = { (__bf16)v.x, (__bf16)v.y, (__bf16)v.z, (__bf16)v.w };
    *(bf16x4*)&dst[(size_t)i * 4] = o;
}

// ---------------------------------------------------------------------------
// m97-style 128x128 GEMM core + XOR-swizzled LDS (verified r15/r16).
// LDS block b of row r holds global 8-elem block b^(r&7); read col
// (ks*32+lg*8)^((lq&7)<<3); gload16 dest linear (rule #21).
// ---------------------------------------------------------------------------
#define BM 128
#define BN 128
#define BKG 64

struct GemmRegs {
    const unsigned short* ag[4];
    const unsigned short* wg[4];
    unsigned short* la[4];
    unsigned short* lw[4];
    int lq, lg, wr, wc;
};

static __device__ __forceinline__ void gemm_setup(
    GemmRegs& R, const unsigned short* A, const unsigned short* W,
    unsigned short* Asm, unsigned short* Bsm, int bm, int bn, int K)
{
    const int tid = threadIdx.x;
    const int wave = tid >> 6, lane = tid & 63;
    R.lq = lane & 15; R.lg = lane >> 4;
    R.wr = wave >> 1; R.wc = wave & 1;
#pragma unroll
    for (int i = 0; i < 4; ++i) {
        const int flat = wave * 256 + i * 64 + lane;   // 0..1023
        const int row = flat >> 3;
        const int col = ((flat & 7) * 8) ^ ((row & 7) << 3);   // pre-swizzled src
        R.ag[i] = A + (size_t)(bm + row) * K + col;
        R.wg[i] = W + (size_t)(bn + row) * K + col;
        R.la[i] = Asm + (wave * 4 + i) * 512;
        R.lw[i] = Bsm + (wave * 4 + i) * 512;
    }
}

static __device__ __forceinline__ void gemm_mfma_step(
    const GemmRegs& R, unsigned short* Asm, unsigned short* Bsm,
    const int colA[2], f32x4 acc[4][4])
{
    __builtin_amdgcn_s_setprio(1);
#pragma unroll
    for (int ks = 0; ks < 2; ++ks) {
        bf16x8 af[4], wf[4];
#pragma unroll
        for (int m = 0; m < 4; ++m)
            af[m] = *(const bf16x8*)&Asm[(R.wr * 64 + m * 16 + R.lq) * BKG + colA[ks]];
#pragma unroll
        for (int n = 0; n < 4; ++n)
            wf[n] = *(const bf16x8*)&Bsm[(R.wc * 64 + n * 16 + R.lq) * BKG + colA[ks]];
#pragma unroll
        for (int m = 0; m < 4; ++m)
#pragma unroll
            for (int n = 0; n < 4; ++n)
                acc[m][n] = __builtin_amdgcn_mfma_f32_16x16x32_bf16(af[m], wf[n], acc[m][n], 0, 0, 0);
    }
    __builtin_amdgcn_s_setprio(0);
}

static __device__ __forceinline__ void gemm_loop(
    GemmRegs& R, unsigned short* Asm, unsigned short* Bsm, int K, f32x4 acc[4][4])
{
    const int sw = (R.lq & 7) << 3;
    int colA[2];
#pragma unroll
    for (int ks = 0; ks < 2; ++ks)
        colA[ks] = (ks * 32 + R.lg * 8) ^ sw;
    for (int kb = 0; kb < K; kb += BKG) {
        __syncthreads();   // previous tile fully consumed
#pragma unroll
        for (int i = 0; i < 4; ++i) {
            gload16(R.ag[i] + kb, R.la[i]);
            gload16(R.wg[i] + kb, R.lw[i]);
        }
        __syncthreads();   // staged
        gemm_mfma_step(R, Asm, Bsm, colA, acc);
    }
}

// ---------------------------------------------------------------------------
// Fused QKV projection, A staged DIRECTLY from fp32 x (T14 reg-staging:
// float4 x2 -> cvt_pk -> ds_write into the same linear LDS slots gload16
// used; pre-swizzled source col unchanged). Deletes the x bf16-cast pass.
// z selects {Q (scaled), K, V (head-transposed, kv bits 2<->3 swapped per
// 16-t group — PV slot permutation, verified r16)}.
// ---------------------------------------------------------------------------
__global__ __launch_bounds__(256) void qkv128(
    const float* __restrict__ x,
    const unsigned short* __restrict__ Wqb, const unsigned short* __restrict__ Wkb,
    const unsigned short* __restrict__ Wvb,
    const float* __restrict__ bq, const float* __restrict__ bk, const float* __restrict__ bv,
    unsigned short* __restrict__ Qb, unsigned short* __restrict__ Kb,
    unsigned short* __restrict__ Vtb)
{
    __shared__ unsigned short Asm[BM * BKG];
    __shared__ unsigned short Bsm[BN * BKG];
    const int z = blockIdx.z;
    const unsigned short* W = (z == 0) ? Wqb : (z == 1) ? Wkb : Wvb;
    const float* bias = (z == 0) ? bq : (z == 1) ? bk : bv;
    const int bm = blockIdx.x * BM, bn = blockIdx.y * BN;

    const int tid = threadIdx.x;
    const int wave = tid >> 6, lane = tid & 63;
    const int lq = lane & 15, lg = lane >> 4;
    const int wr = wave >> 1, wc = wave & 1;

    const float* ag[4];
    unsigned short* adst[4];
    const unsigned short* wg[4];
    unsigned short* lw[4];
#pragma unroll
    for (int i = 0; i < 4; ++i) {
        const int flat = wave * 256 + i * 64 + lane;
        const int row = flat >> 3;
        const int col = ((flat & 7) * 8) ^ ((row & 7) << 3);   // pre-swizzled src
        ag[i] = x + (size_t)(bm + row) * C_ + col;
        adst[i] = Asm + (size_t)flat * 8;                      // linear LDS slot
        wg[i] = W + (size_t)(bn + row) * C_ + col;
        lw[i] = Bsm + (wave * 4 + i) * 512;
    }
    const int sw = (lq & 7) << 3;
    int colA[2];
#pragma unroll
    for (int ks = 0; ks < 2; ++ks)
        colA[ks] = (ks * 32 + lg * 8) ^ sw;

    GemmRegs R;
    R.lq = lq; R.lg = lg; R.wr = wr; R.wc = wc;

    // prologue: tile 0 x -> regs
    float4 xr[4][2];
#pragma unroll
    for (int i = 0; i < 4; ++i) {
        xr[i][0] = *(const float4*)(ag[i]);
        xr[i][1] = *(const float4*)(ag[i] + 4);
    }

    f32x4 acc[4][4] = {};

    for (int kb = 0; kb < C_; kb += BKG) {
        __syncthreads();   // previous tile fully consumed
#pragma unroll
        for (int i = 0; i < 4; ++i) {
            u32x4 pk = { pack2(xr[i][0].x, xr[i][0].y), pack2(xr[i][0].z, xr[i][0].w),
                         pack2(xr[i][1].x, xr[i][1].y), pack2(xr[i][1].z, xr[i][1].w) };
            *(u32x4*)adst[i] = pk;
            gload16(wg[i] + kb, lw[i]);
        }
        __syncthreads();   // staged (A lgkm + W vmcnt drained at barrier)

        // prefetch next tile's x during MFMA (T14)
        if (kb + BKG < C_) {
#pragma unroll
            for (int i = 0; i < 4; ++i) {
                xr[i][0] = *(const float4*)(ag[i] + kb + BKG);
                xr[i][1] = *(const float4*)(ag[i] + kb + BKG + 4);
            }
        }

        gemm_mfma_step(R, Asm, Bsm, colA, acc);
    }

    // 0.125 * log2(e): QK^T scores land in log2 domain
    const float sc = (z == 0) ? 0.18033688011112042f : 1.0f;
#pragma unroll
    for (int mt = 0; mt < 4; ++mt) {
        const int m0 = bm + wr * 64 + mt * 16 + lg * 4;
#pragma unroll
        for (int nt = 0; nt < 4; ++nt) {
            const int n = bn + wc * 64 + nt * 16 + lq;
            const float b = bias[n];
            if (z == 2) {
                const int tp = (m0 & ~12) | ((m0 & 4) << 1) | ((m0 & 8) >> 1);
                bf16x4 o = { (__bf16)(acc[mt][nt][0] + b), (__bf16)(acc[mt][nt][1] + b),
                             (__bf16)(acc[mt][nt][2] + b), (__bf16)(acc[mt][nt][3] + b) };
                *(bf16x4*)&Vtb[(size_t)n * T_ + tp] = o;
            } else {
                unsigned short* Y = (z == 0) ? Qb : Kb;
#pragma unroll
                for (int r = 0; r < 4; ++r)
                    Y[(size_t)(m0 + r) * C_ + n] =
                        __builtin_bit_cast(unsigned short, (__bf16)((acc[mt][nt][r] + b) * sc));
            }
        }
    }
}

// ---------------------------------------------------------------------------
// Output projection: fp32 out + bias (verified r16)
// ---------------------------------------------------------------------------
__global__ __launch_bounds__(256) void out128(
    const unsigned short* __restrict__ ctxb, const unsigned short* __restrict__ Wob,
    const float* __restrict__ bo, float* __restrict__ out)
{
    __shared__ unsigned short Asm[BM * BKG];
    __shared__ unsigned short Bsm[BN * BKG];
    const int bm = blockIdx.x * BM, bn = blockIdx.y * BN;

    GemmRegs R;
    gemm_setup(R, ctxb, Wob, Asm, Bsm, bm, bn, C_);
    f32x4 acc[4][4] = {};
    gemm_loop(R, Asm, Bsm, C_, acc);

#pragma unroll
    for (int mt = 0; mt < 4; ++mt) {
        const int m0 = bm + R.wr * 64 + mt * 16 + R.lg * 4;
#pragma unroll
        for (int nt = 0; nt < 4; ++nt) {
            const int n = bn + R.wc * 64 + nt * 16 + R.lq;
            const float b = bo[n];
#pragma unroll
            for (int r = 0; r < 4; ++r)
                out[(size_t)(m0 + r) * C_ + n] = acc[mt][nt][r] + b;
        }
    }
}

// ---------------------------------------------------------------------------
// Flash attention (verified r16): 4-wave blocks (QBLK=128), dbuf K/V LDS,
// 1 barrier/tile, p = exp2(s), own-register PV B-frags (V permutation baked
// into Vtb), T14 reg-staging, KVBLK=64, 32 KB LDS, SPLITS=2, grid 768.
// ---------------------------------------------------------------------------
#define SPLITS 2
#define KVTILES (T_ / 64 / SPLITS)   // 32

__global__ __launch_bounds__(256, 3) void attn32s(
    const unsigned short* __restrict__ Qb, const unsigned short* __restrict__ Kb,
    const unsigned short* __restrict__ Vtb, unsigned short* __restrict__ Opart,
    float* __restrict__ lpart)
{
    __shared__ unsigned short Ks[2][64 * 64];
    __shared__ unsigned short Vs[2][64 * 64];

    const int tid = threadIdx.x;
    const int wave = tid >> 6, lane = tid & 63;
    const int lq = lane & 31, hi = lane >> 5;

    // XCD swizzle: 768 blocks = 8 XCD x 96
    const int bid = blockIdx.x;
    const int sw = (bid & 7) * 96 + (bid >> 3);
    const int split = sw / 384;
    const int rem = sw - split * 384;
    const int h = rem >> 5, qt = rem & 31;     // 32 q-tiles of 128 per head
    const int q0 = qt * 128 + wave * 32;
    const int kv0 = split * (T_ / SPLITS);

    const int swz = (lq & 7) << 4;
    int rof[4];
#pragma unroll
    for (int ks = 0; ks < 4; ++ks)
        rof[ks] = lq * 128 + ((hi * 16 + ks * 32) ^ swz);

    // Q B-frags: lane holds Q[q0+lq][ks*16 + hi*8 + i]
    bf16x8 qf[4];
    {
        const unsigned short* qp = Qb + (size_t)(q0 + lq) * C_ + h * D_ + hi * 8;
#pragma unroll
        for (int ks = 0; ks < 4; ++ks) qf[ks] = *(const bf16x8*)(qp + ks * 16);
    }

    // T14 staging, split across 4 waves: slot f = j*256 + tid
    const char* gk[2];
    const char* gv[2];
    char* kds[2];
    char* vds[2];
#pragma unroll
    for (int j = 0; j < 2; ++j) {
        const int f = j * 256 + tid;
        const int row = f >> 3;
        const int col = (f & 7) * 16;
        gk[j] = (const char*)Kb + (size_t)(kv0 + row) * (C_ * 2) + h * (D_ * 2) + col;
        gv[j] = (const char*)Vtb + (size_t)(h * D_ + row) * (T_ * 2) + kv0 * 2 + col;
        kds[j] = (char*)&Ks[0][0] + row * 128 + (col ^ ((row & 7) << 4));
        vds[j] = (char*)&Vs[0][0] + row * 128 + (col ^ ((row & 7) << 4));
    }

    u16x8 kreg[2], vreg[2];
#pragma unroll
    for (int j = 0; j < 2; ++j) {     // tile 0 -> regs
        kreg[j] = *(const u16x8*)(gk[j]);
        vreg[j] = *(const u16x8*)(gv[j]);
    }
#pragma unroll
    for (int j = 0; j < 2; ++j) {     // tile 0 -> buf 0
        *(u16x8*)kds[j] = kreg[j];
        *(u16x8*)vds[j] = vreg[j];
    }
    __syncthreads();
#pragma unroll
    for (int j = 0; j < 2; ++j) {     // tile 1 -> regs
        kreg[j] = *(const u16x8*)(gk[j] + 64 * (C_ * 2));
        vreg[j] = *(const u16x8*)(gv[j] + 128);
    }

    f32x16 oacc0 = {}, oacc1 = {};
    float lrun = 0.f;

    for (int it = 0; it < KVTILES; ++it) {
        const int cur = it & 1;
        const char* kb = (const char*)&Ks[cur][0];
        const char* vb = (const char*)&Vs[cur][0];

        // S^T = K · Q^T
        f32x16 s0 = {}, s1 = {};
        __builtin_amdgcn_s_setprio(1);
#pragma unroll
        for (int ks = 0; ks < 4; ++ks) {
            bf16x8 kf0 = *(const bf16x8*)(kb + rof[ks]);
            bf16x8 kf1 = *(const bf16x8*)(kb + 4096 + rof[ks]);
            s0 = __builtin_amdgcn_mfma_f32_32x32x16_bf16(kf0, qf[ks], s0, 0, 0, 0);
            s1 = __builtin_amdgcn_mfma_f32_32x32x16_bf16(kf1, qf[ks], s1, 0, 0, 0);
        }
        __builtin_amdgcn_s_setprio(0);

        // p = exp2(s)
#pragma unroll
        for (int r = 0; r < 16; ++r) {
            s0[r] = fast_exp2(s0[r]);
            s1[r] = fast_exp2(s1[r]);
        }
        {   // l-sum (off critical path)
            float ps[8];
#pragma unroll
            for (int r = 0; r < 8; ++r)
                ps[r] = (s0[r] + s0[r + 8]) + (s1[r] + s1[r + 8]);
            ps[0] += ps[4]; ps[1] += ps[5]; ps[2] += ps[6]; ps[3] += ps[7];
            float pt = (ps[0] + ps[1]) + (ps[2] + ps[3]);
            lrun += pt + __shfl_xor(pt, 32);
        }

        // P^T B-frags = lane's OWN regs (V slot-permutation in Vtb)
        bf16x8 pf[4];
        {
            u32x4 a0 = { pack2(s0[0], s0[1]), pack2(s0[2], s0[3]),
                         pack2(s0[4], s0[5]), pack2(s0[6], s0[7]) };
            pf[0] = __builtin_bit_cast(bf16x8, a0);
            u32x4 a1 = { pack2(s0[8], s0[9]), pack2(s0[10], s0[11]),
                         pack2(s0[12], s0[13]), pack2(s0[14], s0[15]) };
            pf[1] = __builtin_bit_cast(bf16x8, a1);
            u32x4 a2 = { pack2(s1[0], s1[1]), pack2(s1[2], s1[3]),
                         pack2(s1[4], s1[5]), pack2(s1[6], s1[7]) };
            pf[2] = __builtin_bit_cast(bf16x8, a2);
            u32x4 a3 = { pack2(s1[8], s1[9]), pack2(s1[10], s1[11]),
                         pack2(s1[12], s1[13]), pack2(s1[14], s1[15]) };
            pf[3] = __builtin_bit_cast(bf16x8, a3);
        }

        // PV: O^T += V^T · P^T
        __builtin_amdgcn_s_setprio(1);
#pragma unroll
        for (int ks = 0; ks < 4; ++ks) {
            bf16x8 vf0 = *(const bf16x8*)(vb + rof[ks]);
            bf16x8 vf1 = *(const bf16x8*)(vb + 4096 + rof[ks]);
            oacc0 = __builtin_amdgcn_mfma_f32_32x32x16_bf16(vf0, pf[ks], oacc0, 0, 0, 0);
            oacc1 = __builtin_amdgcn_mfma_f32_32x32x16_bf16(vf1, pf[ks], oacc1, 0, 0, 0);
        }
        __builtin_amdgcn_s_setprio(0);

        // stage tile it+1 regs -> buf[cur^1]; then issue tile it+2 loads.
        if (it + 1 < KVTILES) {
            const int nxt = (cur ^ 1) * 8192;
#pragma unroll
            for (int j = 0; j < 2; ++j) {
                *(u16x8*)(kds[j] + nxt) = kreg[j];
                *(u16x8*)(vds[j] + nxt) = vreg[j];
            }
            if (it + 2 < KVTILES) {
                const size_t ko = (size_t)(it + 2) * 64 * (C_ * 2);
                const size_t vo = (size_t)(it + 2) * 128;
#pragma unroll
                for (int j = 0; j < 2; ++j) {
                    kreg[j] = *(const u16x8*)(gk[j] + ko);
                    vreg[j] = *(const u16x8*)(gv[j] + vo);
                }
            }
        }
        __syncthreads();   // buf[cur^1] staged; all reads of buf[cur] done
    }

    // epilogue: partial (unnormalized) O -> Opart, l -> lpart
    unsigned short* op = Opart + ((size_t)(split * H_ + h) * T_ + q0 + lq) * 64;
#pragma unroll
    for (int k = 0; k < 4; ++k) {
        bf16x4 o0 = { (__bf16)oacc0[4 * k + 0], (__bf16)oacc0[4 * k + 1],
                      (__bf16)oacc0[4 * k + 2], (__bf16)oacc0[4 * k + 3] };
        *(bf16x4*)&op[8 * k + 4 * hi] = o0;
        bf16x4 o1 = { (__bf16)oacc1[4 * k + 0], (__bf16)oacc1[4 * k + 1],
                      (__bf16)oacc1[4 * k + 2], (__bf16)oacc1[4 * k + 3] };
        *(bf16x4*)&op[32 + 8 * k + 4 * hi] = o1;
    }
    if (hi == 0)
        lpart[(size_t)(split * H_ + h) * T_ + q0 + lq] = lrun;
}

// ---------------------------------------------------------------------------
// Combine the 2 kv-split partials: ctx = sum_s O_s / sum_s l_s (verified r16)
// ---------------------------------------------------------------------------
__global__ __launch_bounds__(256) void combine2(
    const unsigned short* __restrict__ Opart, const float* __restrict__ lpart,
    unsigned short* __restrict__ ctxb)
{
    const int idx = blockIdx.x * 256 + threadIdx.x;   // < T_*H_*16
    const int dq = idx & 15;
    const int ht = idx >> 4;
    const int h = ht >> 12;          // T_ = 4096 = 2^12
    const int t = ht & (T_ - 1);

    const float l0 = lpart[(size_t)h * T_ + t];
    const float l1 = lpart[(size_t)(H_ + h) * T_ + t];
    const float inv = 1.f / (l0 + l1);
    const bf16x4 a0 = *(const bf16x4*)&Opart[((size_t)h * T_ + t) * 64 + dq * 4];
    const bf16x4 a1 = *(const bf16x4*)&Opart[((size_t)(H_ + h) * T_ + t) * 64 + dq * 4];
    bf16x4 r;
#pragma unroll
    for (int i = 0; i < 4; ++i)
        r[i] = (__bf16)(((float)a0[i] + (float)a1[i]) * inv);
    *(bf16x4*)&ctxb[(size_t)t * C_ + h * D_ + dq * 4] = r;
}

// ---------------------------------------------------------------------------
extern "C" void kernel_launch(void* const* d_in, const int* in_sizes, int n_in,
                              void* d_out, int out_size, void* d_ws, size_t ws_size,
                              hipStream_t stream) {
    (void)in_sizes; (void)n_in; (void)out_size; (void)ws_size;
    const float* x  = (const float*)d_in[0];
    const float* Wq = (const float*)d_in[1];
    const float* bq = (const float*)d_in[2];
    const float* Wk = (const float*)d_in[3];
    const float* bk = (const float*)d_in[4];
    const float* Wv = (const float*)d_in[5];
    const float* bv = (const float*)d_in[6];
    const float* Wo = (const float*)d_in[7];
    const float* bo = (const float*)d_in[8];
    float* out = (float*)d_out;

    unsigned short* ws    = (unsigned short*)d_ws;
    unsigned short* Wqb   = ws;
    unsigned short* Wkb   = Wqb + CC_;
    unsigned short* Wvb   = Wkb + CC_;
    unsigned short* Wob   = Wvb + CC_;
    unsigned short* Qb    = Wob + CC_;
    unsigned short* Kb    = Qb + TC_;
    unsigned short* Vtb   = Kb + TC_;     // [H][D][T] (t bits 2<->3 swapped per 16)
    unsigned short* ctxb  = Vtb + TC_;
    unsigned short* Opart = ctxb + TC_;   // [2][H][T][64] bf16
    float* lpart = (float*)(Opart + 2 * TC_);   // [2][H][T] f32

    dim3 gw(CC_ / 4 / 256, 4);      // all four weights, one launch
    f2b4_kernel<<<gw, 256, 0, stream>>>(Wq, Wk, Wv, Wo, Wqb);

    dim3 gq(T_ / BM, C_ / BN, 3);   // 32 x 6 x 3
    qkv128<<<gq, 256, 0, stream>>>(x, Wqb, Wkb, Wvb, bq, bk, bv, Qb, Kb, Vtb);

    attn32s<<<768, 256, 0, stream>>>(Qb, Kb, Vtb, Opart, lpart);
    combine2<<<(T_ * H_ * 16) / 256, 256, 0, stream>>>(Opart, lpart, ctxb);

    dim3 go(T_ / BM, C_ / BN);      // 32 x 6
    out128<<<go, 256, 0, stream>>>(ctxb, Wob, bo, out);
}

// Round 19
// 117.509 us; speedup vs baseline: 1.1049x; 1.0720x over previous
//
#include <hip/hip_runtime.h>
#include <math.h>

#define T_ 4096
#define C_ 768
#define H_ 12
#define D_ 64
#define TC_ ((size_t)T_ * C_)
#define CC_ ((size_t)C_ * C_)

typedef __attribute__((ext_vector_type(8))) __bf16 bf16x8;
typedef __attribute__((ext_vector_type(4))) __bf16 bf16x4;
typedef __attribute__((ext_vector_type(2))) __bf16 bf16x2;
typedef __attribute__((ext_vector_type(4))) float f32x4;
typedef __attribute__((ext_vector_type(16))) float f32x16;
typedef __attribute__((ext_vector_type(8))) unsigned short u16x8;
typedef __attribute__((ext_vector_type(4))) unsigned int u32x4;

// Softmax shift folded out entirely: p = exp2(s) (scores in log2 units,
// |s| <~ 8.5 -> p <= ~362, l <= ~7e3; uniform factor cancels in O/l).

static __device__ __forceinline__ float fast_exp2(float x) {
#if __has_builtin(__builtin_amdgcn_exp2f)
    return __builtin_amdgcn_exp2f(x);
#else
    return exp2f(x);
#endif
}

// pack two f32 -> u32 of 2 bf16 (compiler emits v_cvt_pk_bf16_f32)
static __device__ __forceinline__ unsigned pack2(float a, float b) {
    bf16x2 v = { (__bf16)a, (__bf16)b };
    return __builtin_bit_cast(unsigned, v);
}

// global (16B per lane) -> LDS direct, wave-uniform LDS base + lane*16
static __device__ __forceinline__ void gload16(const void* g, void* l) {
    __builtin_amdgcn_global_load_lds(
        (const __attribute__((address_space(1))) unsigned int*)g,
        (__attribute__((address_space(3))) unsigned int*)l, 16, 0, 0);
}

// ---------------------------------------------------------------------------
// fp32 -> bf16 convert (RNE), n4 = n/4
// ---------------------------------------------------------------------------
__global__ void f2b_kernel(const float* __restrict__ in,
                           unsigned short* __restrict__ out, int n4) {
    int i = blockIdx.x * blockDim.x + threadIdx.x;
    const int stride = gridDim.x * blockDim.x;
    for (; i < n4; i += stride) {
        float4 v = ((const float4*)in)[i];
        bf16x4 o = { (__bf16)v.x, (__bf16)v.y, (__bf16)v.z, (__bf16)v.w };
        *(bf16x4*)&out[(size_t)i * 4] = o;
    }
}

// 4 weight matrices (each CC_ elems) in one launch; dst contiguous at out+y*CC_
__global__ void f2b4_kernel(const float* __restrict__ w0, const float* __restrict__ w1,
                            const float* __restrict__ w2, const float* __restrict__ w3,
                            unsigned short* __restrict__ out) {
    const float* src = (blockIdx.y == 0) ? w0 : (blockIdx.y == 1) ? w1
                     : (blockIdx.y == 2) ? w2 : w3;
    unsigned short* dst = out + (size_t)blockIdx.y * CC_;
    const int i = blockIdx.x * blockDim.x + threadIdx.x;   // < CC_/4
    float4 v = ((const float4*)src)[i];
    bf16x4 o = { (__bf16)v.x, (__bf16)v.y, (__bf16)v.z, (__bf16)v.w };
    *(bf16x4*)&dst[(size_t)i * 4] = o;
}

// ---------------------------------------------------------------------------
// m97-style 128x128 GEMM core + XOR-swizzled LDS (verified r15/r16).
// LDS block b of row r holds global 8-elem block b^(r&7); read col
// (ks*32+lg*8)^((lq&7)<<3); gload16 dest linear (rule #21).
// ---------------------------------------------------------------------------
#define BM 128
#define BN 128
#define BKG 64

struct GemmRegs {
    const unsigned short* ag[4];
    const unsigned short* wg[4];
    unsigned short* la[4];
    unsigned short* lw[4];
    int lq, lg, wr, wc;
};

static __device__ __forceinline__ void gemm_setup(
    GemmRegs& R, const unsigned short* A, const unsigned short* W,
    unsigned short* Asm, unsigned short* Bsm, int bm, int bn, int K)
{
    const int tid = threadIdx.x;
    const int wave = tid >> 6, lane = tid & 63;
    R.lq = lane & 15; R.lg = lane >> 4;
    R.wr = wave >> 1; R.wc = wave & 1;
#pragma unroll
    for (int i = 0; i < 4; ++i) {
        const int flat = wave * 256 + i * 64 + lane;   // 0..1023
        const int row = flat >> 3;
        const int col = ((flat & 7) * 8) ^ ((row & 7) << 3);   // pre-swizzled src
        R.ag[i] = A + (size_t)(bm + row) * K + col;
        R.wg[i] = W + (size_t)(bn + row) * K + col;
        R.la[i] = Asm + (wave * 4 + i) * 512;
        R.lw[i] = Bsm + (wave * 4 + i) * 512;
    }
}

static __device__ __forceinline__ void gemm_mfma_step(
    const GemmRegs& R, unsigned short* Asm, unsigned short* Bsm,
    const int colA[2], f32x4 acc[4][4])
{
    __builtin_amdgcn_s_setprio(1);
#pragma unroll
    for (int ks = 0; ks < 2; ++ks) {
        bf16x8 af[4], wf[4];
#pragma unroll
        for (int m = 0; m < 4; ++m)
            af[m] = *(const bf16x8*)&Asm[(R.wr * 64 + m * 16 + R.lq) * BKG + colA[ks]];
#pragma unroll
        for (int n = 0; n < 4; ++n)
            wf[n] = *(const bf16x8*)&Bsm[(R.wc * 64 + n * 16 + R.lq) * BKG + colA[ks]];
#pragma unroll
        for (int m = 0; m < 4; ++m)
#pragma unroll
            for (int n = 0; n < 4; ++n)
                acc[m][n] = __builtin_amdgcn_mfma_f32_16x16x32_bf16(af[m], wf[n], acc[m][n], 0, 0, 0);
    }
    __builtin_amdgcn_s_setprio(0);
}

static __device__ __forceinline__ void gemm_loop(
    GemmRegs& R, unsigned short* Asm, unsigned short* Bsm, int K, f32x4 acc[4][4])
{
    const int sw = (R.lq & 7) << 3;
    int colA[2];
#pragma unroll
    for (int ks = 0; ks < 2; ++ks)
        colA[ks] = (ks * 32 + R.lg * 8) ^ sw;
    for (int kb = 0; kb < K; kb += BKG) {
        __syncthreads();   // previous tile fully consumed
#pragma unroll
        for (int i = 0; i < 4; ++i) {
            gload16(R.ag[i] + kb, R.la[i]);
            gload16(R.wg[i] + kb, R.lw[i]);
        }
        __syncthreads();   // staged
        gemm_mfma_step(R, Asm, Bsm, colA, acc);
    }
}

// Fused QKV projection: z selects {Q (scaled), K, V (head-transposed)}.
// V stores with kv bits 2<->3 swapped per 16-t group (PV slot permutation,
// verified r16) so attn's PV B-frag is the lane's OWN registers.
__global__ __launch_bounds__(256) void qkv128(
    const unsigned short* __restrict__ xb,
    const unsigned short* __restrict__ Wqb, const unsigned short* __restrict__ Wkb,
    const unsigned short* __restrict__ Wvb,
    const float* __restrict__ bq, const float* __restrict__ bk, const float* __restrict__ bv,
    unsigned short* __restrict__ Qb, unsigned short* __restrict__ Kb,
    unsigned short* __restrict__ Vtb)
{
    __shared__ unsigned short Asm[BM * BKG];
    __shared__ unsigned short Bsm[BN * BKG];
    const int z = blockIdx.z;
    const unsigned short* W = (z == 0) ? Wqb : (z == 1) ? Wkb : Wvb;
    const float* bias = (z == 0) ? bq : (z == 1) ? bk : bv;
    const int bm = blockIdx.x * BM, bn = blockIdx.y * BN;

    GemmRegs R;
    gemm_setup(R, xb, W, Asm, Bsm, bm, bn, C_);
    f32x4 acc[4][4] = {};
    gemm_loop(R, Asm, Bsm, C_, acc);

    // 0.125 * log2(e): QK^T scores land in log2 domain
    const float sc = (z == 0) ? 0.18033688011112042f : 1.0f;
#pragma unroll
    for (int mt = 0; mt < 4; ++mt) {
        const int m0 = bm + R.wr * 64 + mt * 16 + R.lg * 4;
#pragma unroll
        for (int nt = 0; nt < 4; ++nt) {
            const int n = bn + R.wc * 64 + nt * 16 + R.lq;
            const float b = bias[n];
            if (z == 2) {
                const int tp = (m0 & ~12) | ((m0 & 4) << 1) | ((m0 & 8) >> 1);
                bf16x4 o = { (__bf16)(acc[mt][nt][0] + b), (__bf16)(acc[mt][nt][1] + b),
                             (__bf16)(acc[mt][nt][2] + b), (__bf16)(acc[mt][nt][3] + b) };
                *(bf16x4*)&Vtb[(size_t)n * T_ + tp] = o;
            } else {
                unsigned short* Y = (z == 0) ? Qb : Kb;
#pragma unroll
                for (int r = 0; r < 4; ++r)
                    Y[(size_t)(m0 + r) * C_ + n] =
                        __builtin_bit_cast(unsigned short, (__bf16)((acc[mt][nt][r] + b) * sc));
            }
        }
    }
}

// Output projection: fp32 out + bias (verified r16)
__global__ __launch_bounds__(256) void out128(
    const unsigned short* __restrict__ ctxb, const unsigned short* __restrict__ Wob,
    const float* __restrict__ bo, float* __restrict__ out)
{
    __shared__ unsigned short Asm[BM * BKG];
    __shared__ unsigned short Bsm[BN * BKG];
    const int bm = blockIdx.x * BM, bn = blockIdx.y * BN;

    GemmRegs R;
    gemm_setup(R, ctxb, Wob, Asm, Bsm, bm, bn, C_);
    f32x4 acc[4][4] = {};
    gemm_loop(R, Asm, Bsm, C_, acc);

#pragma unroll
    for (int mt = 0; mt < 4; ++mt) {
        const int m0 = bm + R.wr * 64 + mt * 16 + R.lg * 4;
#pragma unroll
        for (int nt = 0; nt < 4; ++nt) {
            const int n = bn + R.wc * 64 + nt * 16 + R.lq;
            const float b = bo[n];
#pragma unroll
            for (int r = 0; r < 4; ++r)
                out[(size_t)(m0 + r) * C_ + n] = acc[mt][nt][r] + b;
        }
    }
}

// ---------------------------------------------------------------------------
// Flash attention (verified r16): 4-wave blocks (QBLK=128), dbuf K/V LDS,
// 1 barrier/tile, p = exp2(s), own-register PV B-frags (V permutation baked
// into Vtb), T14 reg-staging, KVBLK=64, 32 KB LDS, SPLITS=2, grid 768.
// r19 change: cross-half l-reduce deferred to epilogue (one shfl total
// instead of one per tile; FP sum-order change only).
// ---------------------------------------------------------------------------
#define SPLITS 2
#define KVTILES (T_ / 64 / SPLITS)   // 32

__global__ __launch_bounds__(256, 3) void attn32s(
    const unsigned short* __restrict__ Qb, const unsigned short* __restrict__ Kb,
    const unsigned short* __restrict__ Vtb, unsigned short* __restrict__ Opart,
    float* __restrict__ lpart)
{
    __shared__ unsigned short Ks[2][64 * 64];
    __shared__ unsigned short Vs[2][64 * 64];

    const int tid = threadIdx.x;
    const int wave = tid >> 6, lane = tid & 63;
    const int lq = lane & 31, hi = lane >> 5;

    // XCD swizzle: 768 blocks = 8 XCD x 96
    const int bid = blockIdx.x;
    const int sw = (bid & 7) * 96 + (bid >> 3);
    const int split = sw / 384;
    const int rem = sw - split * 384;
    const int h = rem >> 5, qt = rem & 31;     // 32 q-tiles of 128 per head
    const int q0 = qt * 128 + wave * 32;
    const int kv0 = split * (T_ / SPLITS);

    const int swz = (lq & 7) << 4;
    int rof[4];
#pragma unroll
    for (int ks = 0; ks < 4; ++ks)
        rof[ks] = lq * 128 + ((hi * 16 + ks * 32) ^ swz);

    // Q B-frags: lane holds Q[q0+lq][ks*16 + hi*8 + i]
    bf16x8 qf[4];
    {
        const unsigned short* qp = Qb + (size_t)(q0 + lq) * C_ + h * D_ + hi * 8;
#pragma unroll
        for (int ks = 0; ks < 4; ++ks) qf[ks] = *(const bf16x8*)(qp + ks * 16);
    }

    // T14 staging, split across 4 waves: slot f = j*256 + tid
    const char* gk[2];
    const char* gv[2];
    char* kds[2];
    char* vds[2];
#pragma unroll
    for (int j = 0; j < 2; ++j) {
        const int f = j * 256 + tid;
        const int row = f >> 3;
        const int col = (f & 7) * 16;
        gk[j] = (const char*)Kb + (size_t)(kv0 + row) * (C_ * 2) + h * (D_ * 2) + col;
        gv[j] = (const char*)Vtb + (size_t)(h * D_ + row) * (T_ * 2) + kv0 * 2 + col;
        kds[j] = (char*)&Ks[0][0] + row * 128 + (col ^ ((row & 7) << 4));
        vds[j] = (char*)&Vs[0][0] + row * 128 + (col ^ ((row & 7) << 4));
    }

    u16x8 kreg[2], vreg[2];
#pragma unroll
    for (int j = 0; j < 2; ++j) {     // tile 0 -> regs
        kreg[j] = *(const u16x8*)(gk[j]);
        vreg[j] = *(const u16x8*)(gv[j]);
    }
#pragma unroll
    for (int j = 0; j < 2; ++j) {     // tile 0 -> buf 0
        *(u16x8*)kds[j] = kreg[j];
        *(u16x8*)vds[j] = vreg[j];
    }
    __syncthreads();
#pragma unroll
    for (int j = 0; j < 2; ++j) {     // tile 1 -> regs
        kreg[j] = *(const u16x8*)(gk[j] + 64 * (C_ * 2));
        vreg[j] = *(const u16x8*)(gv[j] + 128);
    }

    f32x16 oacc0 = {}, oacc1 = {};
    float lrun = 0.f;   // lane-local partial (own 32 kvs); cross-half at end

    for (int it = 0; it < KVTILES; ++it) {
        const int cur = it & 1;
        const char* kb = (const char*)&Ks[cur][0];
        const char* vb = (const char*)&Vs[cur][0];

        // S^T = K · Q^T
        f32x16 s0 = {}, s1 = {};
        __builtin_amdgcn_s_setprio(1);
#pragma unroll
        for (int ks = 0; ks < 4; ++ks) {
            bf16x8 kf0 = *(const bf16x8*)(kb + rof[ks]);
            bf16x8 kf1 = *(const bf16x8*)(kb + 4096 + rof[ks]);
            s0 = __builtin_amdgcn_mfma_f32_32x32x16_bf16(kf0, qf[ks], s0, 0, 0, 0);
            s1 = __builtin_amdgcn_mfma_f32_32x32x16_bf16(kf1, qf[ks], s1, 0, 0, 0);
        }
        __builtin_amdgcn_s_setprio(0);

        // p = exp2(s)
#pragma unroll
        for (int r = 0; r < 16; ++r) {
            s0[r] = fast_exp2(s0[r]);
            s1[r] = fast_exp2(s1[r]);
        }
        {   // lane-local l partial (cross-half deferred to epilogue)
            float ps[8];
#pragma unroll
            for (int r = 0; r < 8; ++r)
                ps[r] = (s0[r] + s0[r + 8]) + (s1[r] + s1[r + 8]);
            ps[0] += ps[4]; ps[1] += ps[5]; ps[2] += ps[6]; ps[3] += ps[7];
            lrun += (ps[0] + ps[1]) + (ps[2] + ps[3]);
        }

        // P^T B-frags = lane's OWN regs (V slot-permutation in Vtb)
        bf16x8 pf[4];
        {
            u32x4 a0 = { pack2(s0[0], s0[1]), pack2(s0[2], s0[3]),
                         pack2(s0[4], s0[5]), pack2(s0[6], s0[7]) };
            pf[0] = __builtin_bit_cast(bf16x8, a0);
            u32x4 a1 = { pack2(s0[8], s0[9]), pack2(s0[10], s0[11]),
                         pack2(s0[12], s0[13]), pack2(s0[14], s0[15]) };
            pf[1] = __builtin_bit_cast(bf16x8, a1);
            u32x4 a2 = { pack2(s1[0], s1[1]), pack2(s1[2], s1[3]),
                         pack2(s1[4], s1[5]), pack2(s1[6], s1[7]) };
            pf[2] = __builtin_bit_cast(bf16x8, a2);
            u32x4 a3 = { pack2(s1[8], s1[9]), pack2(s1[10], s1[11]),
                         pack2(s1[12], s1[13]), pack2(s1[14], s1[15]) };
            pf[3] = __builtin_bit_cast(bf16x8, a3);
        }

        // PV: O^T += V^T · P^T
        __builtin_amdgcn_s_setprio(1);
#pragma unroll
        for (int ks = 0; ks < 4; ++ks) {
            bf16x8 vf0 = *(const bf16x8*)(vb + rof[ks]);
            bf16x8 vf1 = *(const bf16x8*)(vb + 4096 + rof[ks]);
            oacc0 = __builtin_amdgcn_mfma_f32_32x32x16_bf16(vf0, pf[ks], oacc0, 0, 0, 0);
            oacc1 = __builtin_amdgcn_mfma_f32_32x32x16_bf16(vf1, pf[ks], oacc1, 0, 0, 0);
        }
        __builtin_amdgcn_s_setprio(0);

        // stage tile it+1 regs -> buf[cur^1]; then issue tile it+2 loads.
        if (it + 1 < KVTILES) {
            const int nxt = (cur ^ 1) * 8192;
#pragma unroll
            for (int j = 0; j < 2; ++j) {
                *(u16x8*)(kds[j] + nxt) = kreg[j];
                *(u16x8*)(vds[j] + nxt) = vreg[j];
            }
            if (it + 2 < KVTILES) {
                const size_t ko = (size_t)(it + 2) * 64 * (C_ * 2);
                const size_t vo = (size_t)(it + 2) * 128;
#pragma unroll
                for (int j = 0; j < 2; ++j) {
                    kreg[j] = *(const u16x8*)(gk[j] + ko);
                    vreg[j] = *(const u16x8*)(gv[j] + vo);
                }
            }
        }
        __syncthreads();   // buf[cur^1] staged; all reads of buf[cur] done
    }

    // deferred cross-half l-reduce (both lanes of the pair get the total)
    lrun += __shfl_xor(lrun, 32);

    // epilogue: partial (unnormalized) O -> Opart, l -> lpart
    unsigned short* op = Opart + ((size_t)(split * H_ + h) * T_ + q0 + lq) * 64;
#pragma unroll
    for (int k = 0; k < 4; ++k) {
        bf16x4 o0 = { (__bf16)oacc0[4 * k + 0], (__bf16)oacc0[4 * k + 1],
                      (__bf16)oacc0[4 * k + 2], (__bf16)oacc0[4 * k + 3] };
        *(bf16x4*)&op[8 * k + 4 * hi] = o0;
        bf16x4 o1 = { (__bf16)oacc1[4 * k + 0], (__bf16)oacc1[4 * k + 1],
                      (__bf16)oacc1[4 * k + 2], (__bf16)oacc1[4 * k + 3] };
        *(bf16x4*)&op[32 + 8 * k + 4 * hi] = o1;
    }
    if (hi == 0)
        lpart[(size_t)(split * H_ + h) * T_ + q0 + lq] = lrun;
}

// ---------------------------------------------------------------------------
// Combine the 2 kv-split partials: ctx = sum_s O_s / sum_s l_s (verified r16)
// ---------------------------------------------------------------------------
__global__ __launch_bounds__(256) void combine2(
    const unsigned short* __restrict__ Opart, const float* __restrict__ lpart,
    unsigned short* __restrict__ ctxb)
{
    const int idx = blockIdx.x * 256 + threadIdx.x;   // < T_*H_*16
    const int dq = idx & 15;
    const int ht = idx >> 4;
    const int h = ht >> 12;          // T_ = 4096 = 2^12
    const int t = ht & (T_ - 1);

    const float l0 = lpart[(size_t)h * T_ + t];
    const float l1 = lpart[(size_t)(H_ + h) * T_ + t];
    const float inv = 1.f / (l0 + l1);
    const bf16x4 a0 = *(const bf16x4*)&Opart[((size_t)h * T_ + t) * 64 + dq * 4];
    const bf16x4 a1 = *(const bf16x4*)&Opart[((size_t)(H_ + h) * T_ + t) * 64 + dq * 4];
    bf16x4 r;
#pragma unroll
    for (int i = 0; i < 4; ++i)
        r[i] = (__bf16)(((float)a0[i] + (float)a1[i]) * inv);
    *(bf16x4*)&ctxb[(size_t)t * C_ + h * D_ + dq * 4] = r;
}

// ---------------------------------------------------------------------------
extern "C" void kernel_launch(void* const* d_in, const int* in_sizes, int n_in,
                              void* d_out, int out_size, void* d_ws, size_t ws_size,
                              hipStream_t stream) {
    (void)in_sizes; (void)n_in; (void)out_size; (void)ws_size;
    const float* x  = (const float*)d_in[0];
    const float* Wq = (const float*)d_in[1];
    const float* bq = (const float*)d_in[2];
    const float* Wk = (const float*)d_in[3];
    const float* bk = (const float*)d_in[4];
    const float* Wv = (const float*)d_in[5];
    const float* bv = (const float*)d_in[6];
    const float* Wo = (const float*)d_in[7];
    const float* bo = (const float*)d_in[8];
    float* out = (float*)d_out;

    unsigned short* ws    = (unsigned short*)d_ws;
    unsigned short* xb    = ws;
    unsigned short* Wqb   = xb + TC_;
    unsigned short* Wkb   = Wqb + CC_;
    unsigned short* Wvb   = Wkb + CC_;
    unsigned short* Wob   = Wvb + CC_;
    unsigned short* Qb    = Wob + CC_;
    unsigned short* Kb    = Qb + TC_;
    unsigned short* Vtb   = Kb + TC_;     // [H][D][T] (t bits 2<->3 swapped per 16)
    unsigned short* ctxb  = Vtb + TC_;
    unsigned short* Opart = ctxb + TC_;   // [2][H][T][64] bf16
    float* lpart = (float*)(Opart + 2 * TC_);   // [2][H][T] f32

    f2b_kernel<<<2048, 256, 0, stream>>>(x, xb, (int)(TC_ / 4));
    dim3 gw(CC_ / 4 / 256, 4);      // all four weights, one launch
    f2b4_kernel<<<gw, 256, 0, stream>>>(Wq, Wk, Wv, Wo, Wqb);

    dim3 gq(T_ / BM, C_ / BN, 3);   // 32 x 6 x 3
    qkv128<<<gq, 256, 0, stream>>>(xb, Wqb, Wkb, Wvb, bq, bk, bv, Qb, Kb, Vtb);

    attn32s<<<768, 256, 0, stream>>>(Qb, Kb, Vtb, Opart, lpart);
    combine2<<<(T_ * H_ * 16) / 256, 256, 0, stream>>>(Opart, lpart, ctxb);

    dim3 go(T_ / BM, C_ / BN);      // 32 x 6
    out128<<<go, 256, 0, stream>>>(ctxb, Wob, bo, out);
}